// Round 1
// baseline (12622.632 us; speedup 1.0000x reference)
//
#include <hip/hip_runtime.h>
#include <cstddef>

#define U_DIM 512
#define T_DIM 2048
#define B_DIM 32
#define F_DIM 1024
#define M_DIM (B_DIM * T_DIM)
#define NBLK 8               // blocks per batch
#define UB (U_DIM / NBLK)    // 64 u-states per block

// ---------------------------------------------------------------------------
// GEMM: potentials[m][n] = sum_k x[m][k]*W[k][n] + b[n] (+ boundary at t=0/T-1)
// fp32 vector-ALU (no fp32 MFMA on CDNA4). 128x64 tile, 256 threads, 8x4 micro.
// (unchanged — known good, ~1.2 ms)
// ---------------------------------------------------------------------------
#define BM 128
#define BN 64
#define BK 16

__global__ __launch_bounds__(256) void gemm_kernel(
    const float* __restrict__ x, const float* __restrict__ W,
    const float* __restrict__ bias, const float* __restrict__ lb,
    const float* __restrict__ rb, float* __restrict__ out)
{
  __shared__ float As[BK][BM + 4];
  __shared__ float Bs[BK][BN];
  const int m0 = blockIdx.x * BM;
  const int n0 = blockIdx.y * BN;
  const int tid = threadIdx.x;
  const int tx = tid & 15;
  const int ty = tid >> 4;

  float acc[8][4];
#pragma unroll
  for (int i = 0; i < 8; ++i)
#pragma unroll
    for (int j = 0; j < 4; ++j) acc[i][j] = 0.f;

  for (int k0 = 0; k0 < F_DIM; k0 += BK) {
#pragma unroll
    for (int i = 0; i < 2; ++i) {
      int id = i * 256 + tid;
      int row = id >> 2;
      int c4 = (id & 3) << 2;
      float4 a = *(const float4*)(x + (size_t)(m0 + row) * F_DIM + k0 + c4);
      As[c4 + 0][row] = a.x;
      As[c4 + 1][row] = a.y;
      As[c4 + 2][row] = a.z;
      As[c4 + 3][row] = a.w;
    }
    {
      int krow = tid >> 4;
      int c4 = (tid & 15) << 2;
      *(float4*)(&Bs[krow][c4]) =
          *(const float4*)(W + (size_t)(k0 + krow) * U_DIM + n0 + c4);
    }
    __syncthreads();
#pragma unroll
    for (int k = 0; k < BK; ++k) {
      float a[8], bb[4];
#pragma unroll
      for (int i = 0; i < 8; ++i) a[i] = As[k][ty * 8 + i];
#pragma unroll
      for (int j = 0; j < 4; ++j) bb[j] = Bs[k][tx * 4 + j];
#pragma unroll
      for (int i = 0; i < 8; ++i)
#pragma unroll
        for (int j = 0; j < 4; ++j) acc[i][j] += a[i] * bb[j];
    }
    __syncthreads();
  }

#pragma unroll
  for (int i = 0; i < 8; ++i) {
    int m = m0 + ty * 8 + i;
    int t = m & (T_DIM - 1);
    float4 o;
#pragma unroll
    for (int j = 0; j < 4; ++j) {
      int n = n0 + tx * 4 + j;
      float v = acc[i][j] + bias[n];
      if (t == 0) v += lb[n];
      if (t == T_DIM - 1) v += rb[n];
      ((float*)&o)[j] = v;
    }
    *(float4*)(out + (size_t)m * U_DIM + n0 + tx * 4) = o;
  }
}

// ---------------------------------------------------------------------------
// aux: copy transitions to output tail, build transposed TrT[u][v] in ws,
// write sequence_lengths.
// ---------------------------------------------------------------------------
__global__ void aux_kernel(const float* __restrict__ tr, float* __restrict__ out_tr,
                           float* __restrict__ trT, float* __restrict__ seqlen)
{
  int idx = blockIdx.x * blockDim.x + threadIdx.x;
  if (idx < U_DIM * U_DIM) {
    float v = tr[idx];
    out_tr[idx] = v;
    int r = idx >> 9;   // v
    int c = idx & 511;  // u
    trT[(size_t)c * U_DIM + r] = v;
  }
  if (idx < B_DIM) seqlen[idx] = (float)T_DIM;
}

// zero the per-(batch,block) publish flags (ws is poisoned every launch)
__global__ void init_kernel(unsigned int* __restrict__ flags)
{
  int i = blockIdx.x * blockDim.x + threadIdx.x;
  if (i < B_DIM * NBLK) flags[i] = 0u;
}

// ---------------------------------------------------------------------------
// Viterbi forward scan, full-chip: 256 blocks = 8 u-slice blocks x 32 batches.
// blockIdx: b = blk & 31 (batch-mates share blk%8 -> same-XCD heuristic),
//           j = blk >> 5 (u-slice).
// 512 threads: u_local = tid>>3 (64 u's), vseg = tid&7.
// trT slice held in 16 float4 regs per thread (loaded once).
//
// Sync protocol (low-traffic, no per-poll cache maintenance):
//  * producer: normal stores drained at __syncthreads (each wave does
//    s_waitcnt vmcnt(0) at the barrier), then tid0 RELEASE-stores the
//    per-block monotonic flag flags[b][j] = t (one wbl2 + sc1 store; no RMW).
//  * consumer: tid<8 spin on the 8 flags with RELAXED agent loads (plain sc1
//    loads to the coherence point -- no buffer_inv per poll, L2 stays warm).
//  * exchanged state is read/written with RELAXED agent (sc1) atomics, which
//    bypass potentially-stale L1/L2 by construction -> no acquire-inv needed
//    in the steady-state loop.
//  * bp is a 64 MB write-once stream -> nontemporal stores (keeps per-step
//    dirty-L2 volume, and thus the release wbl2 cost, near zero).
//  * one acquire fence only, before the backtrack (covers bp reads).
// WAR safety on the state double-buffer: block X overwrites buf[(t+1)&1] =
// buf[(t-1)&1] only after seeing all flags >= t, which implies every block
// finished step t and therefore already consumed buf[(t-1)&1].
// ---------------------------------------------------------------------------
__global__ __launch_bounds__(512) void scan_kernel(
    const float* __restrict__ pot, const float* __restrict__ trT,
    float* __restrict__ stateBuf,        // [2][B][U]
    unsigned int* __restrict__ flags,    // [B][NBLK] monotonic step numbers
    unsigned short* __restrict__ bp,     // [T-1][B][U]
    float* __restrict__ outv)            // [B][T]
{
  const int blk = blockIdx.x;
  const int b = blk & (B_DIM - 1);
  const int j = blk >> 5;
  const int tid = threadIdx.x;
  const int u_local = tid >> 3;
  const int vseg = tid & 7;
  const int u = j * UB + u_local;

  __shared__ float sh_state[U_DIM];
  __shared__ float sh_v[U_DIM];
  __shared__ int sh_i[U_DIM];

  // load this thread's transition slice into registers (once)
  float4 trreg[16];
  const float* trRow = trT + (size_t)u * U_DIM;
#pragma unroll
  for (int m = 0; m < 16; ++m)
    trreg[m] = *(const float4*)(trRow + vseg * 4 + m * 32);

  const float* potb = pot + (size_t)b * T_DIM * U_DIM;
  unsigned int* myflags = flags + b * NBLK;

  for (int t = 1; t < T_DIM; ++t) {
    // independent of peers: issue before the wait so latency hides under it
    float p_u = potb[(size_t)t * U_DIM + u];  // 8-lane broadcast

    if (t > 1) {
      // wait for all 8 blocks of this batch to have published state t-1
      if (tid < NBLK) {
        while (__hip_atomic_load(&myflags[tid], __ATOMIC_RELAXED,
                                 __HIP_MEMORY_SCOPE_AGENT) < (unsigned)(t - 1)) {}
      }
      __syncthreads();
      // stage previous state: sc1 loads -> coherent, no cache-inv needed
      sh_state[tid] = __hip_atomic_load(
          &stateBuf[(size_t)((t - 1) & 1) * B_DIM * U_DIM +
                    (size_t)b * U_DIM + tid],
          __ATOMIC_RELAXED, __HIP_MEMORY_SCOPE_AGENT);
    } else {
      // t==1: state0 = potentials[:,0] (written by gemm kernel, same stream)
      sh_state[tid] = potb[tid];
    }
    __syncthreads();

    float best = -3.402823466e38f;
    int bi = 0;
#pragma unroll
    for (int m = 0; m < 16; ++m) {
      float4 st = *(const float4*)(&sh_state[vseg * 4 + m * 32]);
      float4 trv = trreg[m];
      int vbase = vseg * 4 + m * 32;
      float s0 = st.x + trv.x;
      float s1 = st.y + trv.y;
      float s2 = st.z + trv.z;
      float s3 = st.w + trv.w;
      if (s0 > best) { best = s0; bi = vbase; }
      if (s1 > best) { best = s1; bi = vbase + 1; }
      if (s2 > best) { best = s2; bi = vbase + 2; }
      if (s3 > best) { best = s3; bi = vbase + 3; }
    }
    // combine the 8 vseg partials (lanes u_local*8 .. +7), first-max tie rule
#pragma unroll
    for (int d = 1; d < 8; d <<= 1) {
      float ob = __shfl_xor(best, d, 64);
      int oi = __shfl_xor(bi, d, 64);
      if (ob > best || (ob == best && oi < bi)) { best = ob; bi = oi; }
    }
    if (vseg == 0) {
      float ns = best + p_u;
      // sc1 store: goes toward the coherence point, completion tracked by
      // vmcnt and drained at the barrier below
      __hip_atomic_store(
          &stateBuf[(size_t)(t & 1) * B_DIM * U_DIM + (size_t)b * U_DIM + u],
          ns, __ATOMIC_RELAXED, __HIP_MEMORY_SCOPE_AGENT);
      __builtin_nontemporal_store(
          (unsigned short)bi,
          &bp[(size_t)(t - 1) * (B_DIM * U_DIM) + (size_t)b * U_DIM + u]);
    }
    __syncthreads();  // every wave: s_waitcnt vmcnt(0) -> all writes done
    if (tid == 0) {
      // release-store of monotonic flag (wbl2 belt for the nt bp stores)
      __hip_atomic_store(&myflags[j], (unsigned int)t, __ATOMIC_RELEASE,
                         __HIP_MEMORY_SCOPE_AGENT);
    }
  }

  // block j==0 of each batch: final argmax + backtrack
  if (j == 0) {
    if (tid < NBLK) {
      while (__hip_atomic_load(&myflags[tid], __ATOMIC_RELAXED,
                               __HIP_MEMORY_SCOPE_AGENT) <
             (unsigned)(T_DIM - 1)) {}
    }
    __syncthreads();
    // one acquire fence: invalidate possibly-stale L1/L2 lines (bp was
    // written by remote blocks; ws poison from previous launch may linger)
    if (tid == 0) __builtin_amdgcn_fence(__ATOMIC_ACQUIRE, "agent");
    __syncthreads();

    sh_v[tid] = __hip_atomic_load(
        &stateBuf[(size_t)1 * B_DIM * U_DIM + (size_t)b * U_DIM + tid],
        __ATOMIC_RELAXED, __HIP_MEMORY_SCOPE_AGENT);
    sh_i[tid] = tid;
    __syncthreads();
    for (int s = 256; s > 0; s >>= 1) {
      if (tid < s) {
        float a = sh_v[tid], c = sh_v[tid + s];
        int ia = sh_i[tid], ic = sh_i[tid + s];
        if (c > a || (c == a && ic < ia)) { sh_v[tid] = c; sh_i[tid] = ic; }
      }
      __syncthreads();
    }
    if (tid == 0) {
      int tag = sh_i[0];
      outv[(size_t)b * T_DIM + (T_DIM - 1)] = (float)tag;
      for (int t = T_DIM - 1; t >= 1; --t) {
        tag = bp[(size_t)(t - 1) * (B_DIM * U_DIM) + (size_t)b * U_DIM + tag];
        outv[(size_t)b * T_DIM + (t - 1)] = (float)tag;
      }
    }
  }
}

// ---------------------------------------------------------------------------
extern "C" void kernel_launch(void* const* d_in, const int* in_sizes, int n_in,
                              void* d_out, int out_size, void* d_ws, size_t ws_size,
                              hipStream_t stream)
{
  const float* x    = (const float*)d_in[0];
  const float* W    = (const float*)d_in[1];
  const float* bias = (const float*)d_in[2];
  const float* tr   = (const float*)d_in[3];
  const float* lb   = (const float*)d_in[4];
  const float* rb   = (const float*)d_in[5];

  float* out = (float*)d_out;
  float* out_v   = out;                                      // (B,T) viterbi tags
  float* out_pot = out + (size_t)B_DIM * T_DIM;              // (B,T,U) potentials
  float* out_seq = out_pot + (size_t)B_DIM * T_DIM * U_DIM;  // (B,) seq lengths
  float* out_tr  = out_seq + B_DIM;                          // (U,U) transitions

  // ws layout
  float* trT = (float*)d_ws;                                   // 1 MB
  float* stateBuf = trT + (size_t)U_DIM * U_DIM;               // 128 KB
  unsigned int* flags = (unsigned int*)(stateBuf + 2 * B_DIM * U_DIM);  // 1 KB
  unsigned short* bp = (unsigned short*)(flags + B_DIM * NBLK);         // ~64 MB

  hipLaunchKernelGGL(init_kernel, dim3(1), dim3(256), 0, stream, flags);
  hipLaunchKernelGGL(aux_kernel, dim3(1024), dim3(256), 0, stream,
                     tr, out_tr, trT, out_seq);
  hipLaunchKernelGGL(gemm_kernel, dim3(M_DIM / BM, U_DIM / BN), dim3(256), 0,
                     stream, x, W, bias, lb, rb, out_pot);
  hipLaunchKernelGGL(scan_kernel, dim3(NBLK * B_DIM), dim3(512), 0, stream,
                     out_pot, trT, stateBuf, flags, bp, out_v);
}

// Round 2
// 6666.025 us; speedup vs baseline: 1.8936x; 1.8936x over previous
//
#include <hip/hip_runtime.h>
#include <cstddef>

#define U_DIM 512
#define T_DIM 2048
#define B_DIM 32
#define F_DIM 1024
#define M_DIM (B_DIM * T_DIM)
#define NBLK 8               // blocks per batch
#define UB (U_DIM / NBLK)    // 64 u-states per block

// ---------------------------------------------------------------------------
// GEMM: potentials[m][n] = sum_k x[m][k]*W[k][n] + b[n] (+ boundary at t=0/T-1)
// fp32 vector-ALU (no fp32 MFMA on CDNA4). 128x64 tile, 256 threads, 8x4 micro.
// (unchanged — known good, ~1.2 ms)
// ---------------------------------------------------------------------------
#define BM 128
#define BN 64
#define BK 16

__global__ __launch_bounds__(256) void gemm_kernel(
    const float* __restrict__ x, const float* __restrict__ W,
    const float* __restrict__ bias, const float* __restrict__ lb,
    const float* __restrict__ rb, float* __restrict__ out)
{
  __shared__ float As[BK][BM + 4];
  __shared__ float Bs[BK][BN];
  const int m0 = blockIdx.x * BM;
  const int n0 = blockIdx.y * BN;
  const int tid = threadIdx.x;
  const int tx = tid & 15;
  const int ty = tid >> 4;

  float acc[8][4];
#pragma unroll
  for (int i = 0; i < 8; ++i)
#pragma unroll
    for (int j = 0; j < 4; ++j) acc[i][j] = 0.f;

  for (int k0 = 0; k0 < F_DIM; k0 += BK) {
#pragma unroll
    for (int i = 0; i < 2; ++i) {
      int id = i * 256 + tid;
      int row = id >> 2;
      int c4 = (id & 3) << 2;
      float4 a = *(const float4*)(x + (size_t)(m0 + row) * F_DIM + k0 + c4);
      As[c4 + 0][row] = a.x;
      As[c4 + 1][row] = a.y;
      As[c4 + 2][row] = a.z;
      As[c4 + 3][row] = a.w;
    }
    {
      int krow = tid >> 4;
      int c4 = (tid & 15) << 2;
      *(float4*)(&Bs[krow][c4]) =
          *(const float4*)(W + (size_t)(k0 + krow) * U_DIM + n0 + c4);
    }
    __syncthreads();
#pragma unroll
    for (int k = 0; k < BK; ++k) {
      float a[8], bb[4];
#pragma unroll
      for (int i = 0; i < 8; ++i) a[i] = As[k][ty * 8 + i];
#pragma unroll
      for (int j = 0; j < 4; ++j) bb[j] = Bs[k][tx * 4 + j];
#pragma unroll
      for (int i = 0; i < 8; ++i)
#pragma unroll
        for (int j = 0; j < 4; ++j) acc[i][j] += a[i] * bb[j];
    }
    __syncthreads();
  }

#pragma unroll
  for (int i = 0; i < 8; ++i) {
    int m = m0 + ty * 8 + i;
    int t = m & (T_DIM - 1);
    float4 o;
#pragma unroll
    for (int j = 0; j < 4; ++j) {
      int n = n0 + tx * 4 + j;
      float v = acc[i][j] + bias[n];
      if (t == 0) v += lb[n];
      if (t == T_DIM - 1) v += rb[n];
      ((float*)&o)[j] = v;
    }
    *(float4*)(out + (size_t)m * U_DIM + n0 + tx * 4) = o;
  }
}

// ---------------------------------------------------------------------------
// aux: copy transitions to output tail, build transposed TrT[u][v] in ws,
// write sequence_lengths.
// ---------------------------------------------------------------------------
__global__ void aux_kernel(const float* __restrict__ tr, float* __restrict__ out_tr,
                           float* __restrict__ trT, float* __restrict__ seqlen)
{
  int idx = blockIdx.x * blockDim.x + threadIdx.x;
  if (idx < U_DIM * U_DIM) {
    float v = tr[idx];
    out_tr[idx] = v;
    int r = idx >> 9;   // v
    int c = idx & 511;  // u
    trT[(size_t)c * U_DIM + r] = v;
  }
  if (idx < B_DIM) seqlen[idx] = (float)T_DIM;
}

// zero the per-(batch,block) publish flags (ws is poisoned every launch)
__global__ void init_kernel(unsigned int* __restrict__ flags)
{
  int i = blockIdx.x * blockDim.x + threadIdx.x;
  if (i < B_DIM * NBLK) flags[i] = 0u;
}

// ---------------------------------------------------------------------------
// Viterbi forward scan, full-chip: 256 blocks = 8 u-slice blocks x 32 batches.
// blockIdx: b = blk & 31, j = blk >> 5 (u-slice).
// 512 threads: u_local = tid>>3 (64 u's), vseg = tid&7.
// trT slice held in 16 float4 regs per thread (loaded once).
//
// Sync protocol v2 — NO cache-maintenance ops in the per-step loop:
//  * state & flags are exchanged with RELAXED agent (sc1) atomics, which are
//    serviced at the coherence point (R1 empirically proved sc1 stores become
//    visible to remote sc1 loads with no wbl2: the flag store itself did).
//  * ordering state-store -> flag-store comes from __syncthreads(), whose
//    s_waitcnt vmcnt(0) waits for the state store to be ACKED at the
//    coherence point. No RELEASE (= no buffer_wbl2 tag-walk + HBM-drain
//    wait) anywhere in the 2047-step loop. That wbl2 was R1's ~4 us/step.
//  * bp is written with nontemporal plain stores (may sit dirty in L2).
//    Visibility for the final backtrack: ONE agent-release fence (single
//    wbl2) per block AFTER the loop, then publish flag = T_DIM ("done").
//  * backtracker waits for all 8 flags == T_DIM, acquire-fence (buffer_inv,
//    kills stale/poisoned lines), then reads bp with plain cached loads.
// WAR safety on the state double-buffer: block X overwrites buf[(t+1)&1] =
// buf[(t-1)&1] only after seeing all flags >= t, which implies every block
// finished step t and already consumed buf[(t-1)&1].
// ---------------------------------------------------------------------------
__global__ __launch_bounds__(512) void scan_kernel(
    const float* __restrict__ pot, const float* __restrict__ trT,
    float* __restrict__ stateBuf,        // [2][B][U]
    unsigned int* __restrict__ flags,    // [B][NBLK] monotonic step numbers
    unsigned short* __restrict__ bp,     // [T-1][B][U]
    float* __restrict__ outv)            // [B][T]
{
  const int blk = blockIdx.x;
  const int b = blk & (B_DIM - 1);
  const int j = blk >> 5;
  const int tid = threadIdx.x;
  const int u_local = tid >> 3;
  const int vseg = tid & 7;
  const int u = j * UB + u_local;

  __shared__ float sh_state[U_DIM];
  __shared__ float sh_v[U_DIM];
  __shared__ int sh_i[U_DIM];

  // load this thread's transition slice into registers (once)
  float4 trreg[16];
  const float* trRow = trT + (size_t)u * U_DIM;
#pragma unroll
  for (int m = 0; m < 16; ++m)
    trreg[m] = *(const float4*)(trRow + vseg * 4 + m * 32);

  const float* potb = pot + (size_t)b * T_DIM * U_DIM;
  unsigned int* myflags = flags + b * NBLK;

  for (int t = 1; t < T_DIM; ++t) {
    // independent of peers: issue before the wait so latency hides under it
    float p_u = potb[(size_t)t * U_DIM + u];  // 8-lane broadcast

    if (t > 1) {
      // wait for all 8 blocks of this batch to have published state t-1
      if (tid < NBLK) {
        while (__hip_atomic_load(&myflags[tid], __ATOMIC_RELAXED,
                                 __HIP_MEMORY_SCOPE_AGENT) < (unsigned)(t - 1)) {}
      }
      __syncthreads();
      // stage previous state: sc1 loads -> read the coherence point
      sh_state[tid] = __hip_atomic_load(
          &stateBuf[(size_t)((t - 1) & 1) * B_DIM * U_DIM +
                    (size_t)b * U_DIM + tid],
          __ATOMIC_RELAXED, __HIP_MEMORY_SCOPE_AGENT);
    } else {
      // t==1: state0 = potentials[:,0] (written by gemm kernel, same stream)
      sh_state[tid] = potb[tid];
    }
    __syncthreads();

    float best = -3.402823466e38f;
    int bi = 0;
#pragma unroll
    for (int m = 0; m < 16; ++m) {
      float4 st = *(const float4*)(&sh_state[vseg * 4 + m * 32]);
      float4 trv = trreg[m];
      int vbase = vseg * 4 + m * 32;
      float s0 = st.x + trv.x;
      float s1 = st.y + trv.y;
      float s2 = st.z + trv.z;
      float s3 = st.w + trv.w;
      if (s0 > best) { best = s0; bi = vbase; }
      if (s1 > best) { best = s1; bi = vbase + 1; }
      if (s2 > best) { best = s2; bi = vbase + 2; }
      if (s3 > best) { best = s3; bi = vbase + 3; }
    }
    // combine the 8 vseg partials (lanes u_local*8 .. +7), first-max tie rule
#pragma unroll
    for (int d = 1; d < 8; d <<= 1) {
      float ob = __shfl_xor(best, d, 64);
      int oi = __shfl_xor(bi, d, 64);
      if (ob > best || (ob == best && oi < bi)) { best = ob; bi = oi; }
    }
    if (vseg == 0) {
      float ns = best + p_u;
      // relaxed agent (sc1) store: write-through toward coherence point;
      // completion tracked by vmcnt, drained at the barrier below
      __hip_atomic_store(
          &stateBuf[(size_t)(t & 1) * B_DIM * U_DIM + (size_t)b * U_DIM + u],
          ns, __ATOMIC_RELAXED, __HIP_MEMORY_SCOPE_AGENT);
      __builtin_nontemporal_store(
          (unsigned short)bi,
          &bp[(size_t)(t - 1) * (B_DIM * U_DIM) + (size_t)b * U_DIM + u]);
    }
    __syncthreads();  // every wave: s_waitcnt vmcnt(0) -> state store acked
    if (tid == 0) {
      // RELAXED publish: ordering already guaranteed by the barrier's
      // vmcnt(0) drain. No wbl2 in the loop.
      __hip_atomic_store(&myflags[j], (unsigned int)t, __ATOMIC_RELAXED,
                         __HIP_MEMORY_SCOPE_AGENT);
    }
  }

  // One release fence per block (single wbl2): makes the nt bp stores
  // visible device-wide, then publish "done".
  __syncthreads();
  if (tid == 0) {
    __builtin_amdgcn_fence(__ATOMIC_RELEASE, "agent");
    __hip_atomic_store(&myflags[j], (unsigned int)T_DIM, __ATOMIC_RELAXED,
                       __HIP_MEMORY_SCOPE_AGENT);
  }

  // block j==0 of each batch: final argmax + backtrack
  if (j == 0) {
    if (tid < NBLK) {
      while (__hip_atomic_load(&myflags[tid], __ATOMIC_RELAXED,
                               __HIP_MEMORY_SCOPE_AGENT) < (unsigned)T_DIM) {}
    }
    __syncthreads();
    // one acquire fence: invalidate possibly-stale L1/L2 lines (bp was
    // written by remote blocks; ws poison from previous launch may linger)
    if (tid == 0) __builtin_amdgcn_fence(__ATOMIC_ACQUIRE, "agent");
    __syncthreads();

    sh_v[tid] = __hip_atomic_load(
        &stateBuf[(size_t)1 * B_DIM * U_DIM + (size_t)b * U_DIM + tid],
        __ATOMIC_RELAXED, __HIP_MEMORY_SCOPE_AGENT);
    sh_i[tid] = tid;
    __syncthreads();
    for (int s = 256; s > 0; s >>= 1) {
      if (tid < s) {
        float a = sh_v[tid], c = sh_v[tid + s];
        int ia = sh_i[tid], ic = sh_i[tid + s];
        if (c > a || (c == a && ic < ia)) { sh_v[tid] = c; sh_i[tid] = ic; }
      }
      __syncthreads();
    }
    if (tid == 0) {
      int tag = sh_i[0];
      outv[(size_t)b * T_DIM + (T_DIM - 1)] = (float)tag;
      for (int t = T_DIM - 1; t >= 1; --t) {
        tag = bp[(size_t)(t - 1) * (B_DIM * U_DIM) + (size_t)b * U_DIM + tag];
        outv[(size_t)b * T_DIM + (t - 1)] = (float)tag;
      }
    }
  }
}

// ---------------------------------------------------------------------------
extern "C" void kernel_launch(void* const* d_in, const int* in_sizes, int n_in,
                              void* d_out, int out_size, void* d_ws, size_t ws_size,
                              hipStream_t stream)
{
  const float* x    = (const float*)d_in[0];
  const float* W    = (const float*)d_in[1];
  const float* bias = (const float*)d_in[2];
  const float* tr   = (const float*)d_in[3];
  const float* lb   = (const float*)d_in[4];
  const float* rb   = (const float*)d_in[5];

  float* out = (float*)d_out;
  float* out_v   = out;                                      // (B,T) viterbi tags
  float* out_pot = out + (size_t)B_DIM * T_DIM;              // (B,T,U) potentials
  float* out_seq = out_pot + (size_t)B_DIM * T_DIM * U_DIM;  // (B,) seq lengths
  float* out_tr  = out_seq + B_DIM;                          // (U,U) transitions

  // ws layout
  float* trT = (float*)d_ws;                                   // 1 MB
  float* stateBuf = trT + (size_t)U_DIM * U_DIM;               // 128 KB
  unsigned int* flags = (unsigned int*)(stateBuf + 2 * B_DIM * U_DIM);  // 1 KB
  unsigned short* bp = (unsigned short*)(flags + B_DIM * NBLK);         // ~64 MB

  hipLaunchKernelGGL(init_kernel, dim3(1), dim3(256), 0, stream, flags);
  hipLaunchKernelGGL(aux_kernel, dim3(1024), dim3(256), 0, stream,
                     tr, out_tr, trT, out_seq);
  hipLaunchKernelGGL(gemm_kernel, dim3(M_DIM / BM, U_DIM / BN), dim3(256), 0,
                     stream, x, W, bias, lb, rb, out_pot);
  hipLaunchKernelGGL(scan_kernel, dim3(NBLK * B_DIM), dim3(512), 0, stream,
                     out_pot, trT, stateBuf, flags, bp, out_v);
}